// Round 1
// baseline (526.853 us; speedup 1.0000x reference)
//
#include <hip/hip_runtime.h>
#include <math.h>
#include <string.h>

#define SEQ 8192
#define DIM 1024
#define NBATCH 8

struct SDesc {
  int n, Tmax, totalRows;
  int pos[8], A[8], rowbase[8];
  int anc[8][8];
  float cnt[8][8];
};

// Host-side faithful reimplementation of _gen_spine/_analyze/_structures,
// including the levels[lvl+1] OVERWRITE semantics of the reference BFS.
static SDesc build_structs() {
  SDesc H{};
  int spine[24];
  int ns = 3; spine[0] = 0; spine[1] = 2; spine[2] = 4;
  for (;;) {
    long nxt = 2L * (spine[ns-1] + spine[ns-2] + spine[ns-3]);
    if (nxt >= SEQ) break;
    spine[ns++] = (int)nxt;
  }
  int rb = 0;
  for (int i = 0; i < ns; ++i) {
    int pos = spine[i];
    if (pos < 3) continue;  // pos >= seq_len impossible by construction
    // BFS in spine-index space
    bool visited[24] = {false};
    int levels[12][8]; int lcnt[12];
    for (int l = 0; l < 12; ++l) lcnt[l] = 0;
    levels[0][0] = i; lcnt[0] = 1; visited[i] = true;
    int qidx[64], qlvl[64], qh = 0, qt = 0;
    qidx[qt] = i; qlvl[qt] = 0; qt++;
    int maxd = 0;
    while (qh < qt) {
      int cur = qidx[qh], lvl = qlvl[qh]; qh++;
      if (lvl >= 9) break;
      int newl[8], nn = 0;
      if (cur >= 3) {
        for (int d = 1; d <= 3; ++d) {
          int a = cur - d;
          if (!visited[a]) { visited[a] = true; newl[nn++] = a; qidx[qt] = a; qlvl[qt] = lvl + 1; qt++; }
        }
      }
      if (nn) {  // OVERWRITE (matches reference)
        lcnt[lvl+1] = nn;
        for (int k = 0; k < nn; ++k) levels[lvl+1][k] = newl[k];
        if (lvl + 1 > maxd) maxd = lvl + 1;
      }
    }
    // path counts
    float pcv[24]; bool pcs[24];
    for (int k = 0; k < 24; ++k) { pcv[k] = 0.f; pcs[k] = false; }
    pcv[i] = 1.f; pcs[i] = true;
    for (int lvl = maxd; lvl >= 0; --lvl) {
      for (int nidx = 0; nidx < lcnt[lvl]; ++nidx) {
        int node = levels[lvl][nidx];
        if (node == i) continue;
        if (lvl == maxd) { pcv[node] = 1.f; pcs[node] = true; continue; }
        float c = 0.f;
        for (int cidx = 0; cidx < lcnt[lvl+1]; ++cidx) {
          int ch = levels[lvl+1][cidx];
          if (ch >= 3 && node >= ch - 3 && node <= ch - 1) c += pcs[ch] ? pcv[ch] : 0.f;
        }
        if (lvl != 0) { pcv[node] = c; pcs[node] = true; }
      }
    }
    // collect ancestors (levels order, lvl>0); default pc 1 if unset
    int A = 0;
    int sidx = H.n;
    for (int lvl = 1; lvl <= maxd; ++lvl) {
      for (int nidx = 0; nidx < lcnt[lvl]; ++nidx) {
        int node = levels[lvl][nidx];
        H.anc[sidx][A] = spine[node];
        H.cnt[sidx][A] = pcs[node] ? pcv[node] : 1.f;
        A++;
      }
    }
    if (A == 0) continue;
    H.pos[sidx] = pos; H.A[sidx] = A; H.rowbase[sidx] = rb; rb += A;
    H.n++;
  }
  H.totalRows = rb;
  H.Tmax = 0;
  for (int s = 0; s < H.n; ++s) if (H.A[s] > H.Tmax) H.Tmax = H.A[s];
  return H;
}

// ---------------- kernels ----------------

__global__ __launch_bounds__(256) void k_copy(const float4* __restrict__ in,
                                              float4* __restrict__ out, int n4) {
  int i = blockIdx.x * 256 + threadIdx.x;
  int st = gridDim.x * 256;
  for (; i < n4; i += st) out[i] = in[i];
}

__global__ void k_zero(float4* p, int n4) {
  int i = blockIdx.x * 256 + threadIdx.x;
  int st = gridDim.x * 256;
  for (; i < n4; i += st) p[i] = make_float4(0.f, 0.f, 0.f, 0.f);
}

// w[s][a] = softplus( relu(cnt*w1+b1) . w2 + b2 )
__global__ void k_prep(SDesc sd, const float* __restrict__ w1, const float* __restrict__ b1,
                       const float* __restrict__ w2, const float* __restrict__ b2,
                       float* __restrict__ wout) {
  int t = threadIdx.x;           // 64 threads
  int s = t >> 3, a = t & 7;
  if (s < sd.n && a < sd.A[s]) {
    float v = sd.cnt[s][a];
    float acc = 0.f;
    for (int i = 0; i < 64; ++i) {
      float h = v * w1[i] + b1[i];
      if (h > 0.f) acc += h * w2[i];
    }
    float o = acc + b2[0];
    float sp = (o > 0.f) ? (o + log1pf(expf(-o))) : log1pf(expf(o));
    wout[s * 8 + a] = sp;
  }
}

// msg matmul: mraw[row][j] = msg_w[j,:] . [x(anc) | x(pos)] + msg_b[j]
// rows = (rowbase[s]+a)*8+b; 240 rows total. Block: 4 rows staged, 4 waves x 4 j.
__global__ __launch_bounds__(256) void k_msg(SDesc sd, const float* __restrict__ x,
    const float* __restrict__ msg_w, const float* __restrict__ msg_b,
    float* __restrict__ mraw) {
  __shared__ float lin[4][2048];
  int rt = blockIdx.y * 4;
  for (int idx = threadIdx.x; idx < 4 * 512; idx += 256) {
    int r = idx >> 9, c = idx & 511;
    int row = rt + r;
    int rr = row >> 3, b = row & 7;
    int s = 0; while (s + 1 < sd.n && sd.rowbase[s + 1] <= rr) ++s;
    int a = rr - sd.rowbase[s];
    float4 v;
    if (c < 256) v = ((const float4*)(x + ((size_t)b * SEQ + sd.anc[s][a]) * DIM))[c];
    else         v = ((const float4*)(x + ((size_t)b * SEQ + sd.pos[s]) * DIM))[c - 256];
    ((float4*)lin[r])[c] = v;
  }
  __syncthreads();
  int wave = threadIdx.x >> 6, lane = threadIdx.x & 63;
  int jbase = blockIdx.x * 16 + wave * 4;
  for (int jj = 0; jj < 4; ++jj) {
    int j = jbase + jj;
    float4 wv[8];
    const float4* wp = (const float4*)(msg_w + (size_t)j * 2048);
    #pragma unroll
    for (int c = 0; c < 8; ++c) wv[c] = wp[c * 64 + lane];
    for (int r = 0; r < 4; ++r) {
      const float4* hp = (const float4*)lin[r];
      float acc = 0.f;
      #pragma unroll
      for (int c = 0; c < 8; ++c) {
        float4 h4 = hp[c * 64 + lane];
        acc += wv[c].x * h4.x + wv[c].y * h4.y + wv[c].z * h4.z + wv[c].w * h4.w;
      }
      #pragma unroll
      for (int off = 32; off; off >>= 1) acc += __shfl_xor(acc, off);
      if (lane == 0) mraw[(size_t)(rt + r) * DIM + j] = acc + msg_b[j];
    }
  }
}

// in-place LN + exact gelu + per-ancestor scalar
__global__ __launch_bounds__(256) void k_ln(SDesc sd, const float* __restrict__ ln_g,
    const float* __restrict__ ln_b, const float* __restrict__ wsc, float* __restrict__ m) {
  int row = blockIdx.x;
  int rr = row >> 3;
  int s = 0; while (s + 1 < sd.n && sd.rowbase[s + 1] <= rr) ++s;
  int a = rr - sd.rowbase[s];
  float wmul = wsc[s * 8 + a];
  float* mp = m + (size_t)row * DIM;
  int t = threadIdx.x;
  float4 v = ((float4*)mp)[t];
  float sum = v.x + v.y + v.z + v.w;
  float sq  = v.x * v.x + v.y * v.y + v.z * v.z + v.w * v.w;
  #pragma unroll
  for (int off = 32; off; off >>= 1) { sum += __shfl_xor(sum, off); sq += __shfl_xor(sq, off); }
  __shared__ float s1[4], s2[4];
  int wave = t >> 6, lane = t & 63;
  if (lane == 0) { s1[wave] = sum; s2[wave] = sq; }
  __syncthreads();
  sum = s1[0] + s1[1] + s1[2] + s1[3];
  sq  = s2[0] + s2[1] + s2[2] + s2[3];
  float mu  = sum * (1.f / 1024.f);
  float var = sq * (1.f / 1024.f) - mu * mu;
  float inv = rsqrtf(var + 1e-5f);
  float4 g4 = ((const float4*)ln_g)[t];
  float4 b4 = ((const float4*)ln_b)[t];
  float o[4]  = {v.x, v.y, v.z, v.w};
  float gg[4] = {g4.x, g4.y, g4.z, g4.w};
  float bb[4] = {b4.x, b4.y, b4.z, b4.w};
  #pragma unroll
  for (int i = 0; i < 4; ++i) {
    float u = (o[i] - mu) * inv * gg[i] + bb[i];
    float ge = 0.5f * u * (1.f + erff(u * 0.70710678118654752f));
    o[i] = ge * wmul;
  }
  ((float4*)mp)[t] = make_float4(o[0], o[1], o[2], o[3]);
}

// Gi = mseq @ w_ih.T + b_ih   (240 x 3072, K=1024). Block: 8 rows, 4 waves x 8 j.
__global__ __launch_bounds__(256) void k_gi(const float* __restrict__ mseq,
    const float* __restrict__ wih, const float* __restrict__ bih, float* __restrict__ gi) {
  __shared__ float lin[8][1024];
  int rt = blockIdx.y * 8;
  for (int idx = threadIdx.x; idx < 8 * 256; idx += 256) {
    int r = idx >> 8, c = idx & 255;
    ((float4*)lin[r])[c] = ((const float4*)(mseq + (size_t)(rt + r) * DIM))[c];
  }
  __syncthreads();
  int wave = threadIdx.x >> 6, lane = threadIdx.x & 63;
  int jbase = blockIdx.x * 32 + wave * 8;
  for (int jj = 0; jj < 8; ++jj) {
    int j = jbase + jj;
    float4 wv[4];
    const float4* wp = (const float4*)(wih + (size_t)j * 1024);
    #pragma unroll
    for (int c = 0; c < 4; ++c) wv[c] = wp[c * 64 + lane];
    for (int r = 0; r < 8; ++r) {
      const float4* hp = (const float4*)lin[r];
      float acc = 0.f;
      #pragma unroll
      for (int c = 0; c < 4; ++c) {
        float4 h4 = hp[c * 64 + lane];
        acc += wv[c].x * h4.x + wv[c].y * h4.y + wv[c].z * h4.z + wv[c].w * h4.w;
      }
      #pragma unroll
      for (int off = 32; off; off >>= 1) acc += __shfl_xor(acc, off);
      if (lane == 0) gi[(size_t)(rt + r) * 3072 + j] = acc + bih[j];
    }
  }
}

// one GRU step (global step t). gridDim.y = struct s; 8 batch rows staged.
__global__ __launch_bounds__(256) void k_step(SDesc sd, int t,
    const float* __restrict__ whh, const float* __restrict__ bhh,
    const float* __restrict__ gi, const float* __restrict__ hold, float* __restrict__ hnew) {
  int s = blockIdx.y;
  int t0 = sd.Tmax - sd.A[s];
  if (t < t0) return;                 // not yet started; both h buffers stay 0
  int a = t - t0;
  __shared__ float lh[8][1024];
  for (int idx = threadIdx.x; idx < 8 * 256; idx += 256) {
    int r = idx >> 8, c = idx & 255;
    ((float4*)lh[r])[c] = ((const float4*)(hold + (size_t)(s * 8 + r) * DIM))[c];
  }
  __syncthreads();
  int wave = threadIdx.x >> 6, lane = threadIdx.x & 63;
  int jbase = blockIdx.x * 16 + wave * 4;
  for (int jj = 0; jj < 4; ++jj) {
    int j = jbase + jj;
    float4 wr[4], wz[4], wn[4];
    const float4* pr = (const float4*)(whh + (size_t)j * 1024);
    const float4* pz = (const float4*)(whh + (size_t)(1024 + j) * 1024);
    const float4* pn = (const float4*)(whh + (size_t)(2048 + j) * 1024);
    #pragma unroll
    for (int c = 0; c < 4; ++c) { wr[c] = pr[c * 64 + lane]; wz[c] = pz[c * 64 + lane]; wn[c] = pn[c * 64 + lane]; }
    for (int r = 0; r < 8; ++r) {
      const float4* hp = (const float4*)lh[r];
      float ar = 0.f, az = 0.f, an = 0.f;
      #pragma unroll
      for (int c = 0; c < 4; ++c) {
        float4 h4 = hp[c * 64 + lane];
        ar += wr[c].x * h4.x + wr[c].y * h4.y + wr[c].z * h4.z + wr[c].w * h4.w;
        az += wz[c].x * h4.x + wz[c].y * h4.y + wz[c].z * h4.z + wz[c].w * h4.w;
        an += wn[c].x * h4.x + wn[c].y * h4.y + wn[c].z * h4.z + wn[c].w * h4.w;
      }
      #pragma unroll
      for (int off = 32; off; off >>= 1) {
        ar += __shfl_xor(ar, off); az += __shfl_xor(az, off); an += __shfl_xor(an, off);
      }
      if (lane == 0) {
        int srow  = s * 8 + r;
        int girow = (sd.rowbase[s] + a) * 8 + r;
        const float* gp = gi + (size_t)girow * 3072;
        float hr = ar + bhh[j];
        float hz = az + bhh[1024 + j];
        float hn = an + bhh[2048 + j];
        float rg = 1.f / (1.f + expf(-(gp[j] + hr)));
        float zg = 1.f / (1.f + expf(-(gp[1024 + j] + hz)));
        float ng = tanhf(gp[2048 + j] + rg * hn);
        float ho = lh[r][j];
        hnew[(size_t)srow * DIM + j] = (1.f - zg) * ng + zg * ho;
      }
    }
  }
}

// gate + final blended write directly into out rows
__global__ __launch_bounds__(256) void k_gate(SDesc sd, const float* __restrict__ x,
    const float* __restrict__ gw, const float* __restrict__ gb,
    const float* __restrict__ hfin, float* __restrict__ out) {
  __shared__ float lin[4][2048];
  int rt = blockIdx.y * 4;
  for (int idx = threadIdx.x; idx < 4 * 512; idx += 256) {
    int r = idx >> 9, c = idx & 511;
    int srow = rt + r;
    int s = srow >> 3, b = srow & 7;
    float4 v;
    if (c < 256) v = ((const float4*)(hfin + (size_t)srow * DIM))[c];
    else         v = ((const float4*)(x + ((size_t)b * SEQ + sd.pos[s]) * DIM))[c - 256];
    ((float4*)lin[r])[c] = v;
  }
  __syncthreads();
  int wave = threadIdx.x >> 6, lane = threadIdx.x & 63;
  int jbase = blockIdx.x * 16 + wave * 4;
  for (int jj = 0; jj < 4; ++jj) {
    int j = jbase + jj;
    float4 wv[8];
    const float4* wp = (const float4*)(gw + (size_t)j * 2048);
    #pragma unroll
    for (int c = 0; c < 8; ++c) wv[c] = wp[c * 64 + lane];
    for (int r = 0; r < 4; ++r) {
      const float4* hp = (const float4*)lin[r];
      float acc = 0.f;
      #pragma unroll
      for (int c = 0; c < 8; ++c) {
        float4 h4 = hp[c * 64 + lane];
        acc += wv[c].x * h4.x + wv[c].y * h4.y + wv[c].z * h4.z + wv[c].w * h4.w;
      }
      #pragma unroll
      for (int off = 32; off; off >>= 1) acc += __shfl_xor(acc, off);
      if (lane == 0) {
        int srow = rt + r; int s = srow >> 3, b = srow & 7;
        float g = 1.f / (1.f + expf(-(acc + gb[j])));
        float agg = lin[r][j], hc = lin[r][1024 + j];
        out[((size_t)b * SEQ + sd.pos[s]) * DIM + j] = g * agg + (1.f - g) * hc;
      }
    }
  }
}

// ---------------- launch ----------------

extern "C" void kernel_launch(void* const* d_in, const int* in_sizes, int n_in,
                              void* d_out, int out_size, void* d_ws, size_t ws_size,
                              hipStream_t stream) {
  const float* x      = (const float*)d_in[0];
  const float* pw_w1  = (const float*)d_in[1];
  const float* pw_b1  = (const float*)d_in[2];
  const float* pw_w2  = (const float*)d_in[3];
  const float* pw_b2  = (const float*)d_in[4];
  const float* msg_w  = (const float*)d_in[5];
  const float* msg_b  = (const float*)d_in[6];
  const float* ln_g   = (const float*)d_in[7];
  const float* ln_b   = (const float*)d_in[8];
  const float* w_ih   = (const float*)d_in[9];
  const float* w_hh   = (const float*)d_in[10];
  const float* b_ih   = (const float*)d_in[11];
  const float* b_hh   = (const float*)d_in[12];
  const float* gate_w = (const float*)d_in[13];
  const float* gate_b = (const float*)d_in[14];
  float* out = (float*)d_out;
  float* ws  = (float*)d_ws;

  SDesc sd = build_structs();   // n=7, Tmax=5, totalRows=30 for S=8192

  const int R = sd.totalRows;          // 30
  float* wout = ws;                    // 64 floats
  float* mseq = wout + 64;             // R*8*1024 = 245760
  float* gi   = mseq + (size_t)R * 8 * DIM;        // R*8*3072 = 737280
  float* h0   = gi + (size_t)R * 8 * 3072;         // 56*1024
  float* h1   = h0 + (size_t)sd.n * 8 * DIM;

  // big copy (the HBM floor)
  k_copy<<<4096, 256, 0, stream>>>((const float4*)x, (float4*)out, (NBATCH * SEQ * DIM) / 4);

  // zero GRU state double buffer
  k_zero<<<56, 256, 0, stream>>>((float4*)h0, (2 * sd.n * 8 * DIM) / 4);

  // path-weight scalars
  k_prep<<<1, 64, 0, stream>>>(sd, pw_w1, pw_b1, pw_w2, pw_b2, wout);

  // message matmul -> LN/gelu/scale -> GRU input precompute
  k_msg<<<dim3(64, (R * 8) / 4), 256, 0, stream>>>(sd, x, msg_w, msg_b, mseq);
  k_ln<<<R * 8, 256, 0, stream>>>(sd, ln_g, ln_b, wout, mseq);
  k_gi<<<dim3(96, (R * 8) / 8), 256, 0, stream>>>(mseq, w_ih, b_ih, gi);

  // GRU recurrence, right-aligned global steps
  for (int t = 0; t < sd.Tmax; ++t) {
    const float* hr = (t & 1) ? h1 : h0;
    float*       hw = (t & 1) ? h0 : h1;
    k_step<<<dim3(64, sd.n), 256, 0, stream>>>(sd, t, w_hh, b_hh, gi, hr, hw);
  }
  const float* hfin = (sd.Tmax & 1) ? h1 : h0;

  // gate + final blended rows into out
  k_gate<<<dim3(64, sd.n * 2), 256, 0, stream>>>(sd, x, gate_w, gate_b, hfin, out);

  (void)in_sizes; (void)n_in; (void)out_size; (void)ws_size;
}